// Round 1
// baseline (357.769 us; speedup 1.0000x reference)
//
#include <hip/hip_runtime.h>
#include <stdint.h>

#define T_LEN 8192
#define C_LEN 64
#define OUT_LEN 8
#define BTHREADS 512          // fused top-k block size (8 waves)

// ---------------------------------------------------------------------------
// Kernel A: per row (b,t): pred = argmax_c x[b,t,c] (ties -> lowest c),
// conf = max softmax = 1 / sum_c exp(x - max). 16 lanes/row, float4/lane.
// Measured prior session: 45.8 us vs ~44 us BW floor (276 MB @ 6.3 TB/s).
// Unchanged this round — it is at ~91% of its memory roofline.
// ---------------------------------------------------------------------------
__global__ __launch_bounds__(256) void softmax_stats_kernel(
    const float* __restrict__ x, int2* __restrict__ packed, int nrows)
{
    const int tid  = threadIdx.x;
    const int wave = tid >> 6;
    const int lane = tid & 63;
    const int rw   = lane >> 4;   // row-within-wave (0..3)
    const int sub  = lane & 15;   // 16 lanes per row
    const long long row = (long long)blockIdx.x * 16 + wave * 4 + rw;
    if (row >= nrows) return;

    const float4 v = ((const float4*)(x + row * C_LEN))[sub];

    float m = v.x; int mi = sub * 4;
    if (v.y > m) { m = v.y; mi = sub * 4 + 1; }
    if (v.z > m) { m = v.z; mi = sub * 4 + 2; }
    if (v.w > m) { m = v.w; mi = sub * 4 + 3; }

    // sign-corrected monotone float-bits key | ~idx (tie -> lowest idx)
    const unsigned int s0 = __float_as_uint(m);
    const unsigned int u0 = (s0 & 0x80000000u) ? ~s0 : (s0 | 0x80000000u);
    unsigned long long key =
        ((unsigned long long)u0 << 32) | (unsigned int)~mi;

    #pragma unroll
    for (int off = 8; off >= 1; off >>= 1) {
        const unsigned long long o = __shfl_xor(key, off);
        if (o > key) key = o;
    }

    const unsigned int uu = (unsigned int)(key >> 32);
    const float M = __uint_as_float(
        (uu & 0x80000000u) ? (uu ^ 0x80000000u) : ~uu);

    float s = __expf(v.x - M) + __expf(v.y - M)
            + __expf(v.z - M) + __expf(v.w - M);
    #pragma unroll
    for (int off = 8; off >= 1; off >>= 1) s += __shfl_xor(s, off);

    if (sub == 0) {
        int2 o;
        o.x = __float_as_int(1.0f / s);
        o.y = (int)~(unsigned int)(key & 0xffffffffu);
        packed[row] = o;
    }
}

// ---------------------------------------------------------------------------
// Fused top-k kernel: one block per sample. Full 8192-element sample in LDS
// (no halo, no global fallback, no cand round-trip, no second kernel).
// Single-pass top-8: per-thread Batcher sort-8 over 16 strided candidates,
// wave butterfly bitonic top-8 merge, cross-wave merge, direct output.
// Key = voted_float_bits<<32 | ~t  (monotone for voted>0; ~t gives
// lax.top_k's lower-index tie-break). voted==0 marks non-start/pad.
// ---------------------------------------------------------------------------
typedef unsigned long long u64k;

__device__ __forceinline__ void kcswap(u64k& a, u64k& b) {
    if (a < b) { u64k t = a; a = b; b = t; }
}

// Batcher odd-even merge sort, n=8, descending. 19 comparators.
__device__ __forceinline__ void sort8(u64k* k) {
    kcswap(k[0],k[1]); kcswap(k[2],k[3]); kcswap(k[4],k[5]); kcswap(k[6],k[7]);
    kcswap(k[0],k[2]); kcswap(k[1],k[3]); kcswap(k[4],k[6]); kcswap(k[5],k[7]);
    kcswap(k[1],k[2]); kcswap(k[5],k[6]);
    kcswap(k[0],k[4]); kcswap(k[1],k[5]); kcswap(k[2],k[6]); kcswap(k[3],k[7]);
    kcswap(k[2],k[4]); kcswap(k[3],k[5]);
    kcswap(k[1],k[2]); kcswap(k[3],k[4]); kcswap(k[5],k[6]);
}

// a, b: sorted descending. On exit a = top-8 of union, sorted descending.
// t[i] = max(a[i], b[7-i]) is bitonic and holds the 8 largest; clean 4,2,1.
__device__ __forceinline__ void merge_top8(u64k* a, const u64k* b) {
    u64k t[8];
    #pragma unroll
    for (int i = 0; i < 8; ++i) {
        const u64k x = a[i], y = b[7 - i];
        t[i] = x > y ? x : y;
    }
    kcswap(t[0],t[4]); kcswap(t[1],t[5]); kcswap(t[2],t[6]); kcswap(t[3],t[7]);
    kcswap(t[0],t[2]); kcswap(t[1],t[3]); kcswap(t[4],t[6]); kcswap(t[5],t[7]);
    kcswap(t[0],t[1]); kcswap(t[2],t[3]); kcswap(t[4],t[5]); kcswap(t[6],t[7]);
    #pragma unroll
    for (int i = 0; i < 8; ++i) a[i] = t[i];
}

__global__ __launch_bounds__(BTHREADS) void topk_fused_kernel(
    const int2* __restrict__ packed, float* __restrict__ out)
{
    __shared__ short pred_s[T_LEN];
    __shared__ float conf_s[T_LEN];
    __shared__ u64k  wkeys[BTHREADS / 64][OUT_LEN];

    const int tid    = threadIdx.x;
    const int lane   = tid & 63;
    const int wave   = tid >> 6;
    const int sample = blockIdx.x;
    const int2* __restrict__ pp = packed + (long long)sample * T_LEN;

    // Stage the whole sample. Coalesced 8B loads; conflict-free LDS writes.
    #pragma unroll
    for (int i = 0; i < T_LEN / BTHREADS; ++i) {
        const int t = tid + i * BTHREADS;
        const int2 p = pp[t];
        pred_s[t] = (short)p.y;
        conf_s[t] = __int_as_float(p.x);
    }
    __syncthreads();

    // voted key for position t (0 if not a run start). Strided t = tid + j*512
    // keeps all LDS reads conflict-free (consecutive lanes -> consecutive t).
    auto make_key = [&](int t) -> u64k {
        const short p = pred_s[t];
        if (t != 0 && pred_s[t - 1] == p) return 0ull;
        int len = 1;
        while (t + len < T_LEN && pred_s[t + len] == p) ++len;  // E[iters]~1.02
        const float v = conf_s[t] * (float)len;
        return ((u64k)__float_as_uint(v) << 32) | (unsigned int)~t;
    };

    u64k c0[8], c1[8];
    #pragma unroll
    for (int j = 0; j < 8; ++j) c0[j] = make_key(tid + j * BTHREADS);
    #pragma unroll
    for (int j = 0; j < 8; ++j) c1[j] = make_key(tid + (j + 8) * BTHREADS);

    sort8(c0);
    sort8(c1);
    merge_top8(c0, c1);            // thread-local top-8 of its 16 candidates

    // wave butterfly: every lane ends with the wave's top-8, sorted.
    #pragma unroll
    for (int off = 1; off < 64; off <<= 1) {
        u64k o[8];
        #pragma unroll
        for (int j = 0; j < 8; ++j) o[j] = __shfl_xor(c0[j], off);
        merge_top8(c0, o);
    }

    if (lane == 0) {
        #pragma unroll
        for (int j = 0; j < 8; ++j) wkeys[wave][j] = c0[j];
    }
    __syncthreads();

    // cross-wave merge in wave 0 (8 lists -> butterfly over lanes 0..7 dom.)
    if (wave == 0) {
        u64k m[8];
        #pragma unroll
        for (int j = 0; j < 8; ++j) m[j] = wkeys[lane & 7][j];
        #pragma unroll
        for (int off = 1; off < 8; off <<= 1) {
            u64k o[8];
            #pragma unroll
            for (int j = 0; j < 8; ++j) o[j] = __shfl_xor(m[j], off);
            merge_top8(m, o);
        }
        if (lane == 0) {
            #pragma unroll
            for (int r = 0; r < OUT_LEN; ++r) {
                const u64k key = m[r];
                float ov = 0.0f;                          // pad-with-0 path
                if (key != 0ull) {
                    const int tg = (int)~(unsigned int)(key & 0xffffffffu);
                    ov = (float)pred_s[tg];
                }
                out[(long long)sample * OUT_LEN + r] = ov;
            }
        }
    }
}

extern "C" void kernel_launch(void* const* d_in, const int* in_sizes, int n_in,
                              void* d_out, int out_size, void* d_ws, size_t ws_size,
                              hipStream_t stream) {
    const float* x  = (const float*)d_in[0];
    const int total = in_sizes[0];          // B*T*C
    const int nrows = total / C_LEN;        // B*T
    const int B     = nrows / T_LEN;

    int2* packed = (int2*)d_ws;             // nrows * 8B
    float* out = (float*)d_out;

    const int gridA = (nrows + 15) / 16;    // 16 rows per 256-thread block
    softmax_stats_kernel<<<gridA, 256, 0, stream>>>(x, packed, nrows);
    topk_fused_kernel<<<B, BTHREADS, 0, stream>>>(packed, out);
}